// Round 5
// baseline (137.641 us; speedup 1.0000x reference)
//
#include <hip/hip_runtime.h>
#include <hip/hip_bf16.h>

#define NG 8192      // N_GRID
#define NB 64        // BATCH
#define CI 64        // C_IN
#define CO 64        // C_OUT
#define NM 64        // N_MODES
#define NFJ 128      // 2*N_MODES (re/im interleaved)
#define NROWS 4096   // BATCH*C_IN = BATCH*C_OUT

typedef __bf16 bf16x8 __attribute__((ext_vector_type(8)));
typedef float f32x4 __attribute__((ext_vector_type(4)));

#define GLOAD_LDS16(gsrc, ldst)                                                   \
    __builtin_amdgcn_global_load_lds(                                             \
        (const __attribute__((address_space(1))) void*)(gsrc),                    \
        (__attribute__((address_space(3))) void*)(ldst), 16, 0, 0)

// ---------------------------------------------------------------------------
// Workspace layout:
//   [ 0, 2 MB)  __bf16 Ft[128][8192]      fwd basis, PLAIN row-major (no swz)
//   [ 2, 4 MB)  __bf16 Ginv_sw[8192][128] inv basis, 16B-group swizzle ^(n&15)
//   [ 6, 7 MB)  __bf16 M2[4096][128]
//   [ 7, 9 MB)  __bf16 Wtf  mix-weight MFMA B-fragments (64 modes x 32KB slabs)
//   [ 9, 9+split*2 MB)  float XFpT[split][128 j][4096 rows]   (TRANSPOSED)
// ---------------------------------------------------------------------------

// Fused prep. Blocks 0..63: Wtf fragment slabs (one mode each, LDS-transposed,
// coalesced uint4 stores). Blocks 64..8255: basis tables.
__global__ __launch_bounds__(256) void sc_prep(const float* __restrict__ wr,
                                               const float* __restrict__ wi,
                                               __bf16* __restrict__ Ft,
                                               __bf16* __restrict__ Ginv,
                                               __bf16* __restrict__ Wtf) {
    __shared__ __align__(16) __bf16 wlds[16384];   // 32 KB (Wtf blocks only)
    const float W0 = 6.2831853071795864769f / (float)NG;
    if (blockIdx.x >= 64) {
        int idx = (blockIdx.x - 64) * 256 + threadIdx.x;
        if (idx < 128 * NG) {            // Ft plain [j][k]
            int j = idx >> 13, k = idx & (NG - 1);
            int m = j >> 1;
            int t = (m * k) & (NG - 1);
            float s, c;
            __sincosf((float)t * W0, &s, &c);
            Ft[idx] = (__bf16)((j & 1) ? -s : c);
        } else {                         // Ginv_sw (swizzled, idft unchanged)
            int i2 = idx - 128 * NG;
            int n = i2 >> 7, pos = i2 & 127;
            int g = pos >> 3, e = pos & 7;
            int psrc = ((g ^ (n & 15)) << 3) | e;
            int m = psrc >> 1, im = psrc & 1;
            int t = (m * n) & (NG - 1);
            float s, c;
            __sincosf((float)t * W0, &s, &c);
            float v;
            if (im) v = (m == 0) ? 0.0f : (-2.0f / NG) * s;
            else    v = ((m == 0) ? 1.0f : 2.0f) / NG * c;
            Ginv[i2] = (__bf16)v;
        }
    } else {                             // Wtf slab for mode m = blockIdx.x
        const int m = blockIdx.x;
        const int t = threadIdx.x;
        const int o = t & 63, q = t >> 6;        // q: ci-quarter (16 ci each)
        const int ot = o >> 4, l = o & 15;
        float wrv[16], wiv[16];
        #pragma unroll
        for (int cc = 0; cc < 16; ++cc) {
            int ci = q * 16 + cc;
            wrv[cc] = wr[((size_t)ci * 64 + o) * 64 + m];
            wiv[cc] = wi[((size_t)ci * 64 + o) * 64 + m];
        }
        #pragma unroll
        for (int cc = 0; cc < 16; ++cc) {
            int ci = q * 16 + cc;
            int ksa = ci >> 5, ksb = 2 + ksa;
            int kg = (ci >> 3) & 3, e = ci & 7;
            int pos = (kg * 16 + l) * 8 + e;
            wlds[(0*16 + ksa*4 + ot)*512 + pos] = (__bf16)wrv[cc];
            wlds[(0*16 + ksb*4 + ot)*512 + pos] = (__bf16)(-wiv[cc]);
            wlds[(1*16 + ksa*4 + ot)*512 + pos] = (__bf16)wiv[cc];
            wlds[(1*16 + ksb*4 + ot)*512 + pos] = (__bf16)wrv[cc];
        }
        __syncthreads();
        const uint4* src = (const uint4*)wlds;
        uint4* dst = (uint4*)(Wtf + (size_t)m * 16384);
        #pragma unroll
        for (int s = 0; s < 8; ++s)
            dst[s * 256 + t] = src[s * 256 + t];
    }
}

// Kernel 1: split-K DFT GEMM — BARRIER-FREE, LDS-FREE.
// Previous version was latency-bound (MfmaUtil 4%, HBM 12%): each K-step
// ended in __syncthreads after global_load_lds => s_waitcnt vmcnt(0) full
// drain x16 steps with only 2 blocks/CU to cover. Fill kernels prove 87% HBM
// at 10% occupancy when there are NO sync points. So: read A fragments
// directly from global (4 kg-lanes cover 128B contiguous per row = full
// lines), cvt f32->bf16 in-register; read Ft fragments directly (2 MB,
// L2-resident; staging L2-fit data through LDS was pure overhead).
// Accumulation order unchanged (k ascending, 32-chunks) => bit-identical.
__global__ __launch_bounds__(256, 2) void sc_dft(const float* __restrict__ A,
                                                 const __bf16* __restrict__ Ft,
                                                 float* __restrict__ XFp,
                                                 int nsteps) {
    const int tid = threadIdx.x;
    const int w = tid >> 6, lane = tid & 63;
    const int l15 = lane & 15, kg = lane >> 4;
    const int wm = w >> 1, wn = w & 1;
    const int rt = blockIdx.x & 63, sp = blockIdx.x >> 6;
    const int r0 = rt * 64;
    const int ksl = nsteps * 64;                 // k per split
    const size_t kb0 = (size_t)sp * ksl;

    // per-lane base pointers (k-subgroup kg*8 baked in)
    const float*  a0p = A  + (size_t)(r0 + wm*32 + l15) * NG + kb0 + kg*8;
    const float*  a1p = a0p + (size_t)16 * NG;
    const __bf16* bp  = Ft + (size_t)(wn*64 + l15) * NG + kb0 + kg*8;

    f32x4 acc[2][4] = {};

    #pragma unroll 2
    for (int kk = 0; kk < ksl; kk += 32) {
        bf16x8 a[2], b[4];
        {
            float4 lo = *(const float4*)(a0p + kk);
            float4 hi = *(const float4*)(a0p + kk + 4);
            union { __bf16 h[8]; bf16x8 v; } cv;
            cv.h[0]=(__bf16)lo.x; cv.h[1]=(__bf16)lo.y;
            cv.h[2]=(__bf16)lo.z; cv.h[3]=(__bf16)lo.w;
            cv.h[4]=(__bf16)hi.x; cv.h[5]=(__bf16)hi.y;
            cv.h[6]=(__bf16)hi.z; cv.h[7]=(__bf16)hi.w;
            a[0] = cv.v;
        }
        {
            float4 lo = *(const float4*)(a1p + kk);
            float4 hi = *(const float4*)(a1p + kk + 4);
            union { __bf16 h[8]; bf16x8 v; } cv;
            cv.h[0]=(__bf16)lo.x; cv.h[1]=(__bf16)lo.y;
            cv.h[2]=(__bf16)lo.z; cv.h[3]=(__bf16)lo.w;
            cv.h[4]=(__bf16)hi.x; cv.h[5]=(__bf16)hi.y;
            cv.h[6]=(__bf16)hi.z; cv.h[7]=(__bf16)hi.w;
            a[1] = cv.v;
        }
        #pragma unroll
        for (int jt = 0; jt < 4; ++jt)
            b[jt] = *(const bf16x8*)(bp + (size_t)jt * 16 * NG + kk);
        #pragma unroll
        for (int mt = 0; mt < 2; ++mt)
            #pragma unroll
            for (int jt = 0; jt < 4; ++jt)
                acc[mt][jt] = __builtin_amdgcn_mfma_f32_16x16x32_bf16(
                    a[mt], b[jt], acc[mt][jt], 0, 0, 0);
    }

    // Transposed epilogue: XFpT[sp][j][row], f32x4 over 4 consecutive rows.
    #pragma unroll
    for (int mt = 0; mt < 2; ++mt)
        #pragma unroll
        for (int jt = 0; jt < 4; ++jt)
            *(f32x4*)(XFp + ((size_t)sp * NFJ + wn*64 + jt*16 + l15) * NROWS +
                      (r0 + wm*32 + mt*16 + kg*4)) = acc[mt][jt];
}

// Kernel 2: channel mix as per-mode MFMA GEMM [64b x 128(re|im)] x [128 x 64o].
// Split-K reduction fused into staging (contiguous f32x4 runs per split).
__global__ __launch_bounds__(256) void sc_mix(const float* __restrict__ XFp,
                                              const __bf16* __restrict__ Wtf,
                                              __bf16* __restrict__ M2, int nsplit) {
    __shared__ __align__(16) char at[4096];  // [16 b][128] bf16, 16B-grp swz ^b
    const int t = threadIdx.x;
    const int k = blockIdx.x >> 2, bq = blockIdx.x & 3;
    const int lane = t & 63, ot = t >> 6;
    const int l15 = lane & 15, kg = lane >> 4;

    // staging: thread t handles component c (re/im), rows t127*8 .. +7 of slab
    const int c = t >> 7, t127 = t & 127;
    f32x4 s0 = {}, s1 = {};
    {
        const float* src = XFp + (size_t)(2*k + c) * NROWS + bq*1024 + t127*8;
        const size_t pstride = (size_t)NFJ * NROWS;
        if (nsplit == 8) {
            #pragma unroll
            for (int p = 0; p < 8; ++p) {
                s0 += *(const f32x4*)(src + p*pstride);
                s1 += *(const f32x4*)(src + p*pstride + 4);
            }
        } else {
            for (int p = 0; p < nsplit; ++p) {
                s0 += *(const f32x4*)(src + p*pstride);
                s1 += *(const f32x4*)(src + p*pstride + 4);
            }
        }
    }
    {
        const int bl = t127 >> 3;            // batch-within-slab (row/64)
        const int i0 = (t127 & 7) * 8;       // first c_in of the 8-run
        union { __bf16 h[8]; uint4 u; } cv;
        cv.h[0]=(__bf16)s0[0]; cv.h[1]=(__bf16)s0[1];
        cv.h[2]=(__bf16)s0[2]; cv.h[3]=(__bf16)s0[3];
        cv.h[4]=(__bf16)s1[0]; cv.h[5]=(__bf16)s1[1];
        cv.h[6]=(__bf16)s1[2]; cv.h[7]=(__bf16)s1[3];
        *(uint4*)(at + bl*256 + ((((c*64 + i0) >> 3) ^ bl) << 4)) = cv.u;
    }
    __syncthreads();

    bf16x8 a[4];
    #pragma unroll
    for (int ks = 0; ks < 4; ++ks)
        a[ks] = *(const bf16x8*)(at + l15*256 + (((ks*4 + kg) ^ l15) << 4));

    f32x4 accR = {}, accI = {};
    #pragma unroll
    for (int ks = 0; ks < 4; ++ks) {
        bf16x8 b0 = *(const bf16x8*)(Wtf + (size_t)(((k*2+0)*4+ks)*4+ot)*512 + lane*8);
        accR = __builtin_amdgcn_mfma_f32_16x16x32_bf16(a[ks], b0, accR, 0, 0, 0);
    }
    #pragma unroll
    for (int ks = 0; ks < 4; ++ks) {
        bf16x8 b1 = *(const bf16x8*)(Wtf + (size_t)(((k*2+1)*4+ks)*4+ot)*512 + lane*8);
        accI = __builtin_amdgcn_mfma_f32_16x16x32_bf16(a[ks], b1, accI, 0, 0, 0);
    }
    #pragma unroll
    for (int rr = 0; rr < 4; ++rr) {
        int bg = bq*16 + kg*4 + rr;
        size_t r = (size_t)bg * CO + ot*16 + l15;
        ushort2 pk;
        pk.x = __builtin_bit_cast(unsigned short, (__bf16)accR[rr]);
        pk.y = __builtin_bit_cast(unsigned short, (__bf16)accI[rr]);
        *(ushort2*)(M2 + r * NFJ + 2 * k) = pk;
    }
}

// Kernel 3: IDFT GEMM. Block = 128 r x 128 n, 512 thr (waves 4x2),
// LDS 32 KB -> 4 blocks/CU. Grid 2048. MFMA operands swapped (transposed C
// fragment) so each lane holds 4 consecutive n -> 8 dwordx4 stores.
__global__ __launch_bounds__(512) void sc_idft(const __bf16* __restrict__ M2,
                                               const __bf16* __restrict__ Ginv,
                                               float* __restrict__ out) {
    __shared__ __align__(16) char gls[32768];  // [128 n][128 j] bf16, swz ^(n&15)
    const int tid = threadIdx.x;
    const int w = tid >> 6, lane = tid & 63;
    const int l15 = lane & 15, kg = lane >> 4;
    const int wm = w >> 1;            // 0..3 -> 32 rows
    const int wn = w & 1;             // 0..1 -> 64 n
    const int r0 = (blockIdx.x >> 6) * 128;
    const int n0 = (blockIdx.x & 63) * 128;

    #pragma unroll
    for (int s = 0; s < 4; ++s) {
        int cc = s * 512 + tid;
        GLOAD_LDS16(Ginv + (size_t)n0 * NFJ + cc * 8, gls + cc * 16);
    }

    bf16x8 af[2][4];
    #pragma unroll
    for (int mt = 0; mt < 2; ++mt)
        #pragma unroll
        for (int ks = 0; ks < 4; ++ks)
            af[mt][ks] = *(const bf16x8*)(M2 + (size_t)(r0 + wm*32 + mt*16 + l15) * NFJ +
                                          ks*32 + kg*8);
    __syncthreads();

    f32x4 acc[2][4] = {};
    #pragma unroll
    for (int nt = 0; nt < 4; ++nt) {
        int row = wn*64 + nt*16 + l15;
        bf16x8 bfr[4];
        #pragma unroll
        for (int ks = 0; ks < 4; ++ks)
            bfr[ks] = *(const bf16x8*)(gls + row * 256 + (((ks*4 + kg) ^ (row & 15)) << 4));
        #pragma unroll
        for (int mt = 0; mt < 2; ++mt)
            #pragma unroll
            for (int ks = 0; ks < 4; ++ks)
                acc[mt][nt] = __builtin_amdgcn_mfma_f32_16x16x32_bf16(
                    bfr[ks], af[mt][ks], acc[mt][nt], 0, 0, 0);
    }
    // Swapped C layout: col(l15) = output row, row(kg*4+rr) = n -> f32x4 along n.
    #pragma unroll
    for (int mt = 0; mt < 2; ++mt)
        #pragma unroll
        for (int nt = 0; nt < 4; ++nt)
            *(f32x4*)(out + (size_t)(r0 + wm*32 + mt*16 + l15) * NG +
                      n0 + wn*64 + nt*16 + kg*4) = acc[mt][nt];
}

extern "C" void kernel_launch(void* const* d_in, const int* in_sizes, int n_in,
                              void* d_out, int out_size, void* d_ws, size_t ws_size,
                              hipStream_t stream) {
    const float* lhss = (const float*)d_in[0];
    const float* w_real = (const float*)d_in[1];
    const float* w_imag = (const float*)d_in[2];
    float* out = (float*)d_out;

    char* ws = (char*)d_ws;
    __bf16* Ft      = (__bf16*)ws;                     // 2 MB
    __bf16* Ginv_sw = (__bf16*)(ws + (2u << 20));      // 2 MB
    __bf16* M2      = (__bf16*)(ws + (6u << 20));      // 1 MB
    __bf16* Wtf     = (__bf16*)(ws + (7u << 20));      // 2 MB
    float*  XFp     = (float*) (ws + (9u << 20));      // split*2 MB

    int split;
    if      (ws_size >= (25u << 20)) split = 8;
    else if (ws_size >= (17u << 20)) split = 4;
    else if (ws_size >= (13u << 20)) split = 2;
    else                             split = 1;
    int nsteps = 128 / split;

    sc_prep<<<8256, 256, 0, stream>>>(w_real, w_imag, Ft, Ginv_sw, Wtf);
    sc_dft<<<64 * split, 256, 0, stream>>>(lhss, Ft, XFp, nsteps);
    sc_mix<<<256, 256, 0, stream>>>(XFp, Wtf, M2, split);
    sc_idft<<<2048, 512, 0, stream>>>(M2, Ginv_sw, out);
}

// Round 6
// 128.575 us; speedup vs baseline: 1.0705x; 1.0705x over previous
//
#include <hip/hip_runtime.h>
#include <hip/hip_bf16.h>

#define NG 8192      // N_GRID
#define NB 64        // BATCH
#define CI 64        // C_IN
#define CO 64        // C_OUT
#define NM 64        // N_MODES
#define NFJ 128      // 2*N_MODES (re/im interleaved)
#define NROWS 4096   // BATCH*C_IN = BATCH*C_OUT

typedef __bf16 bf16x8 __attribute__((ext_vector_type(8)));
typedef float f32x4 __attribute__((ext_vector_type(4)));

#define GLOAD_LDS16(gsrc, ldst)                                                   \
    __builtin_amdgcn_global_load_lds(                                             \
        (const __attribute__((address_space(1))) void*)(gsrc),                    \
        (__attribute__((address_space(3))) void*)(ldst), 16, 0, 0)

// ---------------------------------------------------------------------------
// Workspace layout:
//   [ 0, 2 MB)  __bf16 Ft[128][8192]      fwd basis, PLAIN row-major (no swz)
//   [ 2, 4 MB)  __bf16 Ginv_sw[8192][128] inv basis, 16B-group swizzle ^(n&15)
//   [ 6, 7 MB)  __bf16 M2[4096][128]
//   [ 7, 9 MB)  __bf16 Wtf  mix-weight MFMA B-fragments (64 modes x 32KB slabs)
//   [ 9, 9+split*2 MB)  float XFpT[split][128 j][4096 rows]   (TRANSPOSED)
// ---------------------------------------------------------------------------

// Fused prep. Blocks 0..63: Wtf fragment slabs (one mode each, LDS-transposed,
// coalesced uint4 stores). Blocks 64..8255: basis tables.
__global__ __launch_bounds__(256) void sc_prep(const float* __restrict__ wr,
                                               const float* __restrict__ wi,
                                               __bf16* __restrict__ Ft,
                                               __bf16* __restrict__ Ginv,
                                               __bf16* __restrict__ Wtf) {
    __shared__ __align__(16) __bf16 wlds[16384];   // 32 KB (Wtf blocks only)
    const float W0 = 6.2831853071795864769f / (float)NG;
    if (blockIdx.x >= 64) {
        int idx = (blockIdx.x - 64) * 256 + threadIdx.x;
        if (idx < 128 * NG) {            // Ft plain [j][k]
            int j = idx >> 13, k = idx & (NG - 1);
            int m = j >> 1;
            int t = (m * k) & (NG - 1);
            float s, c;
            __sincosf((float)t * W0, &s, &c);
            Ft[idx] = (__bf16)((j & 1) ? -s : c);
        } else {                         // Ginv_sw (swizzled, idft unchanged)
            int i2 = idx - 128 * NG;
            int n = i2 >> 7, pos = i2 & 127;
            int g = pos >> 3, e = pos & 7;
            int psrc = ((g ^ (n & 15)) << 3) | e;
            int m = psrc >> 1, im = psrc & 1;
            int t = (m * n) & (NG - 1);
            float s, c;
            __sincosf((float)t * W0, &s, &c);
            float v;
            if (im) v = (m == 0) ? 0.0f : (-2.0f / NG) * s;
            else    v = ((m == 0) ? 1.0f : 2.0f) / NG * c;
            Ginv[i2] = (__bf16)v;
        }
    } else {                             // Wtf slab for mode m = blockIdx.x
        const int m = blockIdx.x;
        const int t = threadIdx.x;
        const int o = t & 63, q = t >> 6;        // q: ci-quarter (16 ci each)
        const int ot = o >> 4, l = o & 15;
        float wrv[16], wiv[16];
        #pragma unroll
        for (int cc = 0; cc < 16; ++cc) {
            int ci = q * 16 + cc;
            wrv[cc] = wr[((size_t)ci * 64 + o) * 64 + m];
            wiv[cc] = wi[((size_t)ci * 64 + o) * 64 + m];
        }
        #pragma unroll
        for (int cc = 0; cc < 16; ++cc) {
            int ci = q * 16 + cc;
            int ksa = ci >> 5, ksb = 2 + ksa;
            int kg = (ci >> 3) & 3, e = ci & 7;
            int pos = (kg * 16 + l) * 8 + e;
            wlds[(0*16 + ksa*4 + ot)*512 + pos] = (__bf16)wrv[cc];
            wlds[(0*16 + ksb*4 + ot)*512 + pos] = (__bf16)(-wiv[cc]);
            wlds[(1*16 + ksa*4 + ot)*512 + pos] = (__bf16)wiv[cc];
            wlds[(1*16 + ksb*4 + ot)*512 + pos] = (__bf16)wrv[cc];
        }
        __syncthreads();
        const uint4* src = (const uint4*)wlds;
        uint4* dst = (uint4*)(Wtf + (size_t)m * 16384);
        #pragma unroll
        for (int s = 0; s < 8; ++s)
            dst[s * 256 + t] = src[s * 256 + t];
    }
}

__device__ __forceinline__ bf16x8 cvt8(float4 lo, float4 hi) {
    union { __bf16 h[8]; bf16x8 v; } cv;
    cv.h[0] = (__bf16)lo.x; cv.h[1] = (__bf16)lo.y;
    cv.h[2] = (__bf16)lo.z; cv.h[3] = (__bf16)lo.w;
    cv.h[4] = (__bf16)hi.x; cv.h[5] = (__bf16)hi.y;
    cv.h[6] = (__bf16)hi.z; cv.h[7] = (__bf16)hi.w;
    return cv.v;
}

// Kernel 1: split-K DFT GEMM — barrier-free, LDS-free, with a HAND-PIPELINED
// depth-2 register double buffer (named variable sets, no arrays -> no
// dynamic indexing, no scratch). R5's version had VGPR_Count=32: the compiler
// scheduled each load adjacent to its use, so every iteration serially paid
// full memory latency (963 GB/s, MfmaUtil 3.4%). Program order below forces
// load(set^1) BEFORE compute(set): >=1 full stage (8 KB/wave) stays in
// flight, compiler must emit counted vmcnt waits.
// Accumulation order unchanged (k ascending, 32-chunks) => bit-identical.
__global__ __launch_bounds__(256, 2) void sc_dft(const float* __restrict__ A,
                                                 const __bf16* __restrict__ Ft,
                                                 float* __restrict__ XFp,
                                                 int nsteps) {
    const int tid = threadIdx.x;
    const int w = tid >> 6, lane = tid & 63;
    const int l15 = lane & 15, kg = lane >> 4;
    const int wm = w >> 1, wn = w & 1;
    const int rt = blockIdx.x & 63, sp = blockIdx.x >> 6;
    const int r0 = rt * 64;
    const int ksl = nsteps * 64;                 // k per split (>=128, mult of 64)
    const size_t kb0 = (size_t)sp * ksl;

    const float*  a0p = A  + (size_t)(r0 + wm*32 + l15) * NG + kb0 + kg*8;
    const float*  a1p = a0p + (size_t)16 * NG;
    const __bf16* bp0 = Ft + (size_t)(wn*64 + l15) * NG + kb0 + kg*8;
    const __bf16* bp1 = bp0 + (size_t)16 * NG;
    const __bf16* bp2 = bp0 + (size_t)32 * NG;
    const __bf16* bp3 = bp0 + (size_t)48 * NG;

    f32x4 acc[2][4] = {};

    float4 A0lo_0, A0hi_0, A1lo_0, A1hi_0;
    float4 A0lo_1, A0hi_1, A1lo_1, A1hi_1;
    uint4  B0_0, B1_0, B2_0, B3_0;
    uint4  B0_1, B1_1, B2_1, B3_1;

#define DFT_LOAD(S, kk)                                                       \
    A0lo_##S = *(const float4*)(a0p + (kk));                                  \
    A0hi_##S = *(const float4*)(a0p + (kk) + 4);                              \
    A1lo_##S = *(const float4*)(a1p + (kk));                                  \
    A1hi_##S = *(const float4*)(a1p + (kk) + 4);                              \
    B0_##S = *(const uint4*)(bp0 + (kk));                                     \
    B1_##S = *(const uint4*)(bp1 + (kk));                                     \
    B2_##S = *(const uint4*)(bp2 + (kk));                                     \
    B3_##S = *(const uint4*)(bp3 + (kk));

#define DFT_COMP(S)                                                           \
    {                                                                         \
        bf16x8 a0 = cvt8(A0lo_##S, A0hi_##S);                                 \
        bf16x8 a1 = cvt8(A1lo_##S, A1hi_##S);                                 \
        bf16x8 b0 = __builtin_bit_cast(bf16x8, B0_##S);                       \
        bf16x8 b1 = __builtin_bit_cast(bf16x8, B1_##S);                       \
        bf16x8 b2 = __builtin_bit_cast(bf16x8, B2_##S);                       \
        bf16x8 b3 = __builtin_bit_cast(bf16x8, B3_##S);                       \
        acc[0][0] = __builtin_amdgcn_mfma_f32_16x16x32_bf16(a0, b0, acc[0][0], 0, 0, 0); \
        acc[0][1] = __builtin_amdgcn_mfma_f32_16x16x32_bf16(a0, b1, acc[0][1], 0, 0, 0); \
        acc[0][2] = __builtin_amdgcn_mfma_f32_16x16x32_bf16(a0, b2, acc[0][2], 0, 0, 0); \
        acc[0][3] = __builtin_amdgcn_mfma_f32_16x16x32_bf16(a0, b3, acc[0][3], 0, 0, 0); \
        acc[1][0] = __builtin_amdgcn_mfma_f32_16x16x32_bf16(a1, b0, acc[1][0], 0, 0, 0); \
        acc[1][1] = __builtin_amdgcn_mfma_f32_16x16x32_bf16(a1, b1, acc[1][1], 0, 0, 0); \
        acc[1][2] = __builtin_amdgcn_mfma_f32_16x16x32_bf16(a1, b2, acc[1][2], 0, 0, 0); \
        acc[1][3] = __builtin_amdgcn_mfma_f32_16x16x32_bf16(a1, b3, acc[1][3], 0, 0, 0); \
    }

    DFT_LOAD(0, 0)
    int kk = 0;
    for (; kk + 64 < ksl; kk += 64) {
        DFT_LOAD(1, kk + 32)
        DFT_COMP(0)
        DFT_LOAD(0, kk + 64)
        DFT_COMP(1)
    }
    DFT_LOAD(1, kk + 32)
    DFT_COMP(0)
    DFT_COMP(1)
#undef DFT_LOAD
#undef DFT_COMP

    // Transposed epilogue: XFpT[sp][j][row], f32x4 over 4 consecutive rows.
    #pragma unroll
    for (int mt = 0; mt < 2; ++mt)
        #pragma unroll
        for (int jt = 0; jt < 4; ++jt)
            *(f32x4*)(XFp + ((size_t)sp * NFJ + wn*64 + jt*16 + l15) * NROWS +
                      (r0 + wm*32 + mt*16 + kg*4)) = acc[mt][jt];
}

// Kernel 2: channel mix as per-mode MFMA GEMM [64b x 128(re|im)] x [128 x 64o].
// Split-K reduction fused into staging (contiguous f32x4 runs per split).
__global__ __launch_bounds__(256) void sc_mix(const float* __restrict__ XFp,
                                              const __bf16* __restrict__ Wtf,
                                              __bf16* __restrict__ M2, int nsplit) {
    __shared__ __align__(16) char at[4096];  // [16 b][128] bf16, 16B-grp swz ^b
    const int t = threadIdx.x;
    const int k = blockIdx.x >> 2, bq = blockIdx.x & 3;
    const int lane = t & 63, ot = t >> 6;
    const int l15 = lane & 15, kg = lane >> 4;

    // staging: thread t handles component c (re/im), rows t127*8 .. +7 of slab
    const int c = t >> 7, t127 = t & 127;
    f32x4 s0 = {}, s1 = {};
    {
        const float* src = XFp + (size_t)(2*k + c) * NROWS + bq*1024 + t127*8;
        const size_t pstride = (size_t)NFJ * NROWS;
        if (nsplit == 8) {
            #pragma unroll
            for (int p = 0; p < 8; ++p) {
                s0 += *(const f32x4*)(src + p*pstride);
                s1 += *(const f32x4*)(src + p*pstride + 4);
            }
        } else {
            for (int p = 0; p < nsplit; ++p) {
                s0 += *(const f32x4*)(src + p*pstride);
                s1 += *(const f32x4*)(src + p*pstride + 4);
            }
        }
    }
    {
        const int bl = t127 >> 3;            // batch-within-slab (row/64)
        const int i0 = (t127 & 7) * 8;       // first c_in of the 8-run
        union { __bf16 h[8]; uint4 u; } cv;
        cv.h[0]=(__bf16)s0[0]; cv.h[1]=(__bf16)s0[1];
        cv.h[2]=(__bf16)s0[2]; cv.h[3]=(__bf16)s0[3];
        cv.h[4]=(__bf16)s1[0]; cv.h[5]=(__bf16)s1[1];
        cv.h[6]=(__bf16)s1[2]; cv.h[7]=(__bf16)s1[3];
        *(uint4*)(at + bl*256 + ((((c*64 + i0) >> 3) ^ bl) << 4)) = cv.u;
    }
    __syncthreads();

    bf16x8 a[4];
    #pragma unroll
    for (int ks = 0; ks < 4; ++ks)
        a[ks] = *(const bf16x8*)(at + l15*256 + (((ks*4 + kg) ^ l15) << 4));

    f32x4 accR = {}, accI = {};
    #pragma unroll
    for (int ks = 0; ks < 4; ++ks) {
        bf16x8 b0 = *(const bf16x8*)(Wtf + (size_t)(((k*2+0)*4+ks)*4+ot)*512 + lane*8);
        accR = __builtin_amdgcn_mfma_f32_16x16x32_bf16(a[ks], b0, accR, 0, 0, 0);
    }
    #pragma unroll
    for (int ks = 0; ks < 4; ++ks) {
        bf16x8 b1 = *(const bf16x8*)(Wtf + (size_t)(((k*2+1)*4+ks)*4+ot)*512 + lane*8);
        accI = __builtin_amdgcn_mfma_f32_16x16x32_bf16(a[ks], b1, accI, 0, 0, 0);
    }
    #pragma unroll
    for (int rr = 0; rr < 4; ++rr) {
        int bg = bq*16 + kg*4 + rr;
        size_t r = (size_t)bg * CO + ot*16 + l15;
        ushort2 pk;
        pk.x = __builtin_bit_cast(unsigned short, (__bf16)accR[rr]);
        pk.y = __builtin_bit_cast(unsigned short, (__bf16)accI[rr]);
        *(ushort2*)(M2 + r * NFJ + 2 * k) = pk;
    }
}

// Kernel 3: IDFT GEMM. Block = 128 r x 128 n, 512 thr (waves 4x2),
// LDS 32 KB -> 4 blocks/CU. Grid 2048. MFMA operands swapped (transposed C
// fragment) so each lane holds 4 consecutive n -> 8 dwordx4 stores.
__global__ __launch_bounds__(512) void sc_idft(const __bf16* __restrict__ M2,
                                               const __bf16* __restrict__ Ginv,
                                               float* __restrict__ out) {
    __shared__ __align__(16) char gls[32768];  // [128 n][128 j] bf16, swz ^(n&15)
    const int tid = threadIdx.x;
    const int w = tid >> 6, lane = tid & 63;
    const int l15 = lane & 15, kg = lane >> 4;
    const int wm = w >> 1;            // 0..3 -> 32 rows
    const int wn = w & 1;             // 0..1 -> 64 n
    const int r0 = (blockIdx.x >> 6) * 128;
    const int n0 = (blockIdx.x & 63) * 128;

    #pragma unroll
    for (int s = 0; s < 4; ++s) {
        int cc = s * 512 + tid;
        GLOAD_LDS16(Ginv + (size_t)n0 * NFJ + cc * 8, gls + cc * 16);
    }

    bf16x8 af[2][4];
    #pragma unroll
    for (int mt = 0; mt < 2; ++mt)
        #pragma unroll
        for (int ks = 0; ks < 4; ++ks)
            af[mt][ks] = *(const bf16x8*)(M2 + (size_t)(r0 + wm*32 + mt*16 + l15) * NFJ +
                                          ks*32 + kg*8);
    __syncthreads();

    f32x4 acc[2][4] = {};
    #pragma unroll
    for (int nt = 0; nt < 4; ++nt) {
        int row = wn*64 + nt*16 + l15;
        bf16x8 bfr[4];
        #pragma unroll
        for (int ks = 0; ks < 4; ++ks)
            bfr[ks] = *(const bf16x8*)(gls + row * 256 + (((ks*4 + kg) ^ (row & 15)) << 4));
        #pragma unroll
        for (int mt = 0; mt < 2; ++mt)
            #pragma unroll
            for (int ks = 0; ks < 4; ++ks)
                acc[mt][nt] = __builtin_amdgcn_mfma_f32_16x16x32_bf16(
                    bfr[ks], af[mt][ks], acc[mt][nt], 0, 0, 0);
    }
    // Swapped C layout: col(l15) = output row, row(kg*4+rr) = n -> f32x4 along n.
    #pragma unroll
    for (int mt = 0; mt < 2; ++mt)
        #pragma unroll
        for (int nt = 0; nt < 4; ++nt)
            *(f32x4*)(out + (size_t)(r0 + wm*32 + mt*16 + l15) * NG +
                      n0 + wn*64 + nt*16 + kg*4) = acc[mt][nt];
}

extern "C" void kernel_launch(void* const* d_in, const int* in_sizes, int n_in,
                              void* d_out, int out_size, void* d_ws, size_t ws_size,
                              hipStream_t stream) {
    const float* lhss = (const float*)d_in[0];
    const float* w_real = (const float*)d_in[1];
    const float* w_imag = (const float*)d_in[2];
    float* out = (float*)d_out;

    char* ws = (char*)d_ws;
    __bf16* Ft      = (__bf16*)ws;                     // 2 MB
    __bf16* Ginv_sw = (__bf16*)(ws + (2u << 20));      // 2 MB
    __bf16* M2      = (__bf16*)(ws + (6u << 20));      // 1 MB
    __bf16* Wtf     = (__bf16*)(ws + (7u << 20));      // 2 MB
    float*  XFp     = (float*) (ws + (9u << 20));      // split*2 MB

    int split;
    if      (ws_size >= (25u << 20)) split = 8;
    else if (ws_size >= (17u << 20)) split = 4;
    else if (ws_size >= (13u << 20)) split = 2;
    else                             split = 1;
    int nsteps = 128 / split;

    sc_prep<<<8256, 256, 0, stream>>>(w_real, w_imag, Ft, Ginv_sw, Wtf);
    sc_dft<<<64 * split, 256, 0, stream>>>(lhss, Ft, XFp, nsteps);
    sc_mix<<<256, 256, 0, stream>>>(XFp, Wtf, M2, split);
    sc_idft<<<2048, 512, 0, stream>>>(M2, Ginv_sw, out);
}

// Round 7
// 97.830 us; speedup vs baseline: 1.4069x; 1.3143x over previous
//
#include <hip/hip_runtime.h>
#include <hip/hip_bf16.h>

#define NG 8192      // N_GRID
#define NB 64        // BATCH
#define CI 64        // C_IN
#define CO 64        // C_OUT
#define NM 64        // N_MODES
#define NFJ 128      // 2*N_MODES (re/im interleaved)
#define NROWS 4096   // BATCH*C_IN = BATCH*C_OUT

typedef __bf16 bf16x8 __attribute__((ext_vector_type(8)));
typedef float f32x4 __attribute__((ext_vector_type(4)));

#define GLOAD_LDS16(gsrc, ldst)                                                   \
    __builtin_amdgcn_global_load_lds(                                             \
        (const __attribute__((address_space(1))) void*)(gsrc),                    \
        (__attribute__((address_space(3))) void*)(ldst), 16, 0, 0)

// ---------------------------------------------------------------------------
// Workspace layout:
//   [ 0, 2 MB)  __bf16 Ft_sw[128][8192]   fwd basis, 16B-group swizzle ^(j&7)
//   [ 2, 4 MB)  __bf16 Ginv_sw[8192][128] inv basis, 16B-group swizzle ^(n&15)
//   [ 6, 7 MB)  __bf16 M2[4096][128]
//   [ 7, 9 MB)  __bf16 Wtf  mix-weight MFMA B-fragments (64 modes x 32KB slabs)
//   [ 9, 9+split*2 MB)  float XFpT[split][128 j][4096 rows]   (TRANSPOSED)
// ---------------------------------------------------------------------------

// Fused prep. Blocks 0..63: Wtf fragment slabs (one mode each, LDS-transposed,
// coalesced uint4 stores). Blocks 64..8255: basis tables (Ft swizzled again).
__global__ __launch_bounds__(256) void sc_prep(const float* __restrict__ wr,
                                               const float* __restrict__ wi,
                                               __bf16* __restrict__ Ft,
                                               __bf16* __restrict__ Ginv,
                                               __bf16* __restrict__ Wtf) {
    __shared__ __align__(16) __bf16 wlds[16384];   // 32 KB (Wtf blocks only)
    const float W0 = 6.2831853071795864769f / (float)NG;
    if (blockIdx.x >= 64) {
        int idx = (blockIdx.x - 64) * 256 + threadIdx.x;
        if (idx < 128 * NG) {            // Ft_sw (16B-group swizzle ^(j&7))
            int j = idx >> 13, pos = idx & (NG - 1);
            int blk = pos >> 6, g = (pos >> 3) & 7, e = pos & 7;
            int ksrc = (blk << 6) + (((g ^ (j & 7)) << 3) | e);
            int m = j >> 1;
            int t = (m * ksrc) & (NG - 1);
            float s, c;
            __sincosf((float)t * W0, &s, &c);
            Ft[idx] = (__bf16)((j & 1) ? -s : c);
        } else {                         // Ginv_sw
            int i2 = idx - 128 * NG;
            int n = i2 >> 7, pos = i2 & 127;
            int g = pos >> 3, e = pos & 7;
            int psrc = ((g ^ (n & 15)) << 3) | e;
            int m = psrc >> 1, im = psrc & 1;
            int t = (m * n) & (NG - 1);
            float s, c;
            __sincosf((float)t * W0, &s, &c);
            float v;
            if (im) v = (m == 0) ? 0.0f : (-2.0f / NG) * s;
            else    v = ((m == 0) ? 1.0f : 2.0f) / NG * c;
            Ginv[i2] = (__bf16)v;
        }
    } else {                             // Wtf slab for mode m = blockIdx.x
        const int m = blockIdx.x;
        const int t = threadIdx.x;
        const int o = t & 63, q = t >> 6;        // q: ci-quarter (16 ci each)
        const int ot = o >> 4, l = o & 15;
        float wrv[16], wiv[16];
        #pragma unroll
        for (int cc = 0; cc < 16; ++cc) {
            int ci = q * 16 + cc;
            wrv[cc] = wr[((size_t)ci * 64 + o) * 64 + m];
            wiv[cc] = wi[((size_t)ci * 64 + o) * 64 + m];
        }
        #pragma unroll
        for (int cc = 0; cc < 16; ++cc) {
            int ci = q * 16 + cc;
            int ksa = ci >> 5, ksb = 2 + ksa;
            int kg = (ci >> 3) & 3, e = ci & 7;
            int pos = (kg * 16 + l) * 8 + e;
            wlds[(0*16 + ksa*4 + ot)*512 + pos] = (__bf16)wrv[cc];
            wlds[(0*16 + ksb*4 + ot)*512 + pos] = (__bf16)(-wiv[cc]);
            wlds[(1*16 + ksa*4 + ot)*512 + pos] = (__bf16)wiv[cc];
            wlds[(1*16 + ksb*4 + ot)*512 + pos] = (__bf16)wrv[cc];
        }
        __syncthreads();
        const uint4* src = (const uint4*)wlds;
        uint4* dst = (uint4*)(Wtf + (size_t)m * 16384);
        #pragma unroll
        for (int s = 0; s < 8; ++s)
            dst[s * 256 + t] = src[s * 256 + t];
    }
}

// Kernel 1: split-K DFT GEMM. R1's proven LDS double-buffered structure
// (64 rows x 128 j, BK=64, 256 thr) + counted-vmcnt barriers (T3/T4) +
// depth-2 A register prefetch. Why: R1's __syncthreads forced vmcnt(0)
// (full drain of the A stream every step -> 2.4 TB/s); barrier-free variants
// collapsed (compiler sank loads, VGPR 32/60, ~1 TB/s). Here barriers are
// kept (they pin the schedule) but the end-of-step wait is a hand-counted
// asm vmcnt(4): F(t+1)'s 4 global_load_lds must land, A(t+2)'s 4 register
// loads STAY IN FLIGHT across the barrier (~1.5 steps of latency cover).
// writeA(t+1)'s register dependency gives a compiler-counted vmcnt(8).
// Accumulation order identical to R1 => bit-identical output.
__global__ __launch_bounds__(256, 2) void sc_dft(const float* __restrict__ A,
                                                 const __bf16* __restrict__ Ft,
                                                 float* __restrict__ XFp,
                                                 int nsteps) {
    __shared__ __align__(16) char smem[49152];
    char* Ab0 = smem;            // 8 KB  [64 r][64 k] bf16, 16B-group swz ^(r&7)
    char* Ab1 = smem + 8192;
    char* Fb0 = smem + 16384;    // 16 KB [128 j][64 k] bf16, swz ^(j&7)
    char* Fb1 = smem + 32768;

    const int tid = threadIdx.x;
    const int w = tid >> 6, lane = tid & 63;
    const int l15 = lane & 15, kg = lane >> 4;
    const int wm = w >> 1, wn = w & 1;
    const int rt = blockIdx.x & 63, sp = blockIdx.x >> 6;
    const int r0 = rt * 64;
    const size_t kb0 = (size_t)sp * nsteps * 64;
    const int swz = l15 & 7;

    float4 avA[4], avB[4];       // two named A register sets (static indices)
    f32x4 acc[2][4] = {};

    auto issueA = [&](int step, float4 (&av)[4]) {
        size_t kb = kb0 + (size_t)step * 64;
        #pragma unroll
        for (int s = 0; s < 4; ++s) {
            int c = s * 256 + tid;
            av[s] = *(const float4*)(A + (size_t)(r0 + (c >> 4)) * NG + kb + (c & 15) * 4);
        }
    };
    auto writeA = [&](const float4 (&av)[4], char* Ab) {
        #pragma unroll
        for (int s = 0; s < 4; ++s) {
            int c = s * 256 + tid, row = c >> 4, cq = c & 15;
            union { __bf16 h[4]; uint2 u; } cv;
            cv.h[0] = (__bf16)av[s].x; cv.h[1] = (__bf16)av[s].y;
            cv.h[2] = (__bf16)av[s].z; cv.h[3] = (__bf16)av[s].w;
            *(uint2*)(Ab + row * 128 + (((cq >> 1) ^ (row & 7)) << 4) + ((cq & 1) << 3)) = cv.u;
        }
    };
    auto stageF = [&](int step, char* Fb) {
        size_t kb = kb0 + (size_t)step * 64;
        #pragma unroll
        for (int s = 0; s < 4; ++s) {
            int cc = s * 256 + tid;
            GLOAD_LDS16(Ft + (size_t)(cc >> 3) * NG + kb + (cc & 7) * 8, Fb + cc * 16);
        }
    };
    auto compute = [&](const char* Ab, const char* Fb) {
        #pragma unroll
        for (int ks2 = 0; ks2 < 2; ++ks2) {
            bf16x8 a[2], b[4];
            #pragma unroll
            for (int mt = 0; mt < 2; ++mt)
                a[mt] = *(const bf16x8*)(Ab + (wm*32 + mt*16 + l15) * 128 +
                                         (((ks2*4 + kg) ^ swz) << 4));
            #pragma unroll
            for (int jt = 0; jt < 4; ++jt)
                b[jt] = *(const bf16x8*)(Fb + (wn*64 + jt*16 + l15) * 128 +
                                         (((ks2*4 + kg) ^ swz) << 4));
            #pragma unroll
            for (int mt = 0; mt < 2; ++mt)
                #pragma unroll
                for (int jt = 0; jt < 4; ++jt)
                    acc[mt][jt] = __builtin_amdgcn_mfma_f32_16x16x32_bf16(
                        a[mt], b[jt], acc[mt][jt], 0, 0, 0);
        }
    };

    // Prologue: F(0)->LDS, A(0)->regs->LDS (one-time full drain), A(1)->regs.
    stageF(0, Fb0);
    __builtin_amdgcn_sched_barrier(0);
    issueA(0, avA);
    writeA(avA, Ab0);                 // implicit wait drains F(0)+A(0)
    issueA(1, avB);
    asm volatile("s_waitcnt lgkmcnt(0)" ::: "memory");
    __builtin_amdgcn_s_barrier();
    __builtin_amdgcn_sched_barrier(0);

    for (int t = 0; t < nsteps; ++t) {
        const bool evn = !(t & 1);
        const char* Ac = evn ? Ab0 : Ab1;
        const char* Fc = evn ? Fb0 : Fb1;
        char* An = evn ? Ab1 : Ab0;
        char* Fn = evn ? Fb1 : Fb0;
        // issue order matters for the counted vmcnt: F(t+1) FIRST (oldest).
        if (t + 1 < nsteps) stageF(t + 1, Fn);
        __builtin_amdgcn_sched_barrier(0);
        if (t + 2 < nsteps) { if (evn) issueA(t + 2, avA); else issueA(t + 2, avB); }
        compute(Ac, Fc);
        if (t + 1 < nsteps) {
            if (evn) writeA(avB, An); else writeA(avA, An);  // vmcnt(8) implicit
            if (t + 2 < nsteps)
                asm volatile("s_waitcnt vmcnt(4)" ::: "memory");   // F(t+1) done, A(t+2) in flight
            else
                asm volatile("s_waitcnt vmcnt(0)" ::: "memory");   // tail: no A outstanding
            asm volatile("s_waitcnt lgkmcnt(0)" ::: "memory");
            __builtin_amdgcn_s_barrier();
            __builtin_amdgcn_sched_barrier(0);
        }
    }

    // Transposed epilogue: XFpT[sp][j][row], f32x4 over 4 consecutive rows.
    #pragma unroll
    for (int mt = 0; mt < 2; ++mt)
        #pragma unroll
        for (int jt = 0; jt < 4; ++jt)
            *(f32x4*)(XFp + ((size_t)sp * NFJ + wn*64 + jt*16 + l15) * NROWS +
                      (r0 + wm*32 + mt*16 + kg*4)) = acc[mt][jt];
}

// Kernel 2: channel mix as per-mode MFMA GEMM [64b x 128(re|im)] x [128 x 64o].
// Split-K reduction fused into staging (contiguous f32x4 runs per split).
__global__ __launch_bounds__(256) void sc_mix(const float* __restrict__ XFp,
                                              const __bf16* __restrict__ Wtf,
                                              __bf16* __restrict__ M2, int nsplit) {
    __shared__ __align__(16) char at[4096];  // [16 b][128] bf16, 16B-grp swz ^b
    const int t = threadIdx.x;
    const int k = blockIdx.x >> 2, bq = blockIdx.x & 3;
    const int lane = t & 63, ot = t >> 6;
    const int l15 = lane & 15, kg = lane >> 4;

    // staging: thread t handles component c (re/im), rows t127*8 .. +7 of slab
    const int c = t >> 7, t127 = t & 127;
    f32x4 s0 = {}, s1 = {};
    {
        const float* src = XFp + (size_t)(2*k + c) * NROWS + bq*1024 + t127*8;
        const size_t pstride = (size_t)NFJ * NROWS;
        if (nsplit == 8) {
            #pragma unroll
            for (int p = 0; p < 8; ++p) {
                s0 += *(const f32x4*)(src + p*pstride);
                s1 += *(const f32x4*)(src + p*pstride + 4);
            }
        } else {
            for (int p = 0; p < nsplit; ++p) {
                s0 += *(const f32x4*)(src + p*pstride);
                s1 += *(const f32x4*)(src + p*pstride + 4);
            }
        }
    }
    {
        const int bl = t127 >> 3;            // batch-within-slab (row/64)
        const int i0 = (t127 & 7) * 8;       // first c_in of the 8-run
        union { __bf16 h[8]; uint4 u; } cv;
        cv.h[0]=(__bf16)s0[0]; cv.h[1]=(__bf16)s0[1];
        cv.h[2]=(__bf16)s0[2]; cv.h[3]=(__bf16)s0[3];
        cv.h[4]=(__bf16)s1[0]; cv.h[5]=(__bf16)s1[1];
        cv.h[6]=(__bf16)s1[2]; cv.h[7]=(__bf16)s1[3];
        *(uint4*)(at + bl*256 + ((((c*64 + i0) >> 3) ^ bl) << 4)) = cv.u;
    }
    __syncthreads();

    bf16x8 a[4];
    #pragma unroll
    for (int ks = 0; ks < 4; ++ks)
        a[ks] = *(const bf16x8*)(at + l15*256 + (((ks*4 + kg) ^ l15) << 4));

    f32x4 accR = {}, accI = {};
    #pragma unroll
    for (int ks = 0; ks < 4; ++ks) {
        bf16x8 b0 = *(const bf16x8*)(Wtf + (size_t)(((k*2+0)*4+ks)*4+ot)*512 + lane*8);
        accR = __builtin_amdgcn_mfma_f32_16x16x32_bf16(a[ks], b0, accR, 0, 0, 0);
    }
    #pragma unroll
    for (int ks = 0; ks < 4; ++ks) {
        bf16x8 b1 = *(const bf16x8*)(Wtf + (size_t)(((k*2+1)*4+ks)*4+ot)*512 + lane*8);
        accI = __builtin_amdgcn_mfma_f32_16x16x32_bf16(a[ks], b1, accI, 0, 0, 0);
    }
    #pragma unroll
    for (int rr = 0; rr < 4; ++rr) {
        int bg = bq*16 + kg*4 + rr;
        size_t r = (size_t)bg * CO + ot*16 + l15;
        ushort2 pk;
        pk.x = __builtin_bit_cast(unsigned short, (__bf16)accR[rr]);
        pk.y = __builtin_bit_cast(unsigned short, (__bf16)accI[rr]);
        *(ushort2*)(M2 + r * NFJ + 2 * k) = pk;
    }
}

// Kernel 3: IDFT GEMM. Block = 128 r x 128 n, 512 thr (waves 4x2),
// LDS 32 KB -> 4 blocks/CU. Grid 2048. MFMA operands swapped (transposed C
// fragment) so each lane holds 4 consecutive n -> 8 dwordx4 stores.
__global__ __launch_bounds__(512) void sc_idft(const __bf16* __restrict__ M2,
                                               const __bf16* __restrict__ Ginv,
                                               float* __restrict__ out) {
    __shared__ __align__(16) char gls[32768];  // [128 n][128 j] bf16, swz ^(n&15)
    const int tid = threadIdx.x;
    const int w = tid >> 6, lane = tid & 63;
    const int l15 = lane & 15, kg = lane >> 4;
    const int wm = w >> 1;            // 0..3 -> 32 rows
    const int wn = w & 1;             // 0..1 -> 64 n
    const int r0 = (blockIdx.x >> 6) * 128;
    const int n0 = (blockIdx.x & 63) * 128;

    #pragma unroll
    for (int s = 0; s < 4; ++s) {
        int cc = s * 512 + tid;
        GLOAD_LDS16(Ginv + (size_t)n0 * NFJ + cc * 8, gls + cc * 16);
    }

    bf16x8 af[2][4];
    #pragma unroll
    for (int mt = 0; mt < 2; ++mt)
        #pragma unroll
        for (int ks = 0; ks < 4; ++ks)
            af[mt][ks] = *(const bf16x8*)(M2 + (size_t)(r0 + wm*32 + mt*16 + l15) * NFJ +
                                          ks*32 + kg*8);
    __syncthreads();

    f32x4 acc[2][4] = {};
    #pragma unroll
    for (int nt = 0; nt < 4; ++nt) {
        int row = wn*64 + nt*16 + l15;
        bf16x8 bfr[4];
        #pragma unroll
        for (int ks = 0; ks < 4; ++ks)
            bfr[ks] = *(const bf16x8*)(gls + row * 256 + (((ks*4 + kg) ^ (row & 15)) << 4));
        #pragma unroll
        for (int mt = 0; mt < 2; ++mt)
            #pragma unroll
            for (int ks = 0; ks < 4; ++ks)
                acc[mt][nt] = __builtin_amdgcn_mfma_f32_16x16x32_bf16(
                    bfr[ks], af[mt][ks], acc[mt][nt], 0, 0, 0);
    }
    // Swapped C layout: col(l15) = output row, row(kg*4+rr) = n -> f32x4 along n.
    #pragma unroll
    for (int mt = 0; mt < 2; ++mt)
        #pragma unroll
        for (int nt = 0; nt < 4; ++nt)
            *(f32x4*)(out + (size_t)(r0 + wm*32 + mt*16 + l15) * NG +
                      n0 + wn*64 + nt*16 + kg*4) = acc[mt][nt];
}

extern "C" void kernel_launch(void* const* d_in, const int* in_sizes, int n_in,
                              void* d_out, int out_size, void* d_ws, size_t ws_size,
                              hipStream_t stream) {
    const float* lhss = (const float*)d_in[0];
    const float* w_real = (const float*)d_in[1];
    const float* w_imag = (const float*)d_in[2];
    float* out = (float*)d_out;

    char* ws = (char*)d_ws;
    __bf16* Ft_sw   = (__bf16*)ws;                     // 2 MB
    __bf16* Ginv_sw = (__bf16*)(ws + (2u << 20));      // 2 MB
    __bf16* M2      = (__bf16*)(ws + (6u << 20));      // 1 MB
    __bf16* Wtf     = (__bf16*)(ws + (7u << 20));      // 2 MB
    float*  XFp     = (float*) (ws + (9u << 20));      // split*2 MB

    int split;
    if      (ws_size >= (25u << 20)) split = 8;
    else if (ws_size >= (17u << 20)) split = 4;
    else if (ws_size >= (13u << 20)) split = 2;
    else                             split = 1;
    int nsteps = 128 / split;

    sc_prep<<<8256, 256, 0, stream>>>(w_real, w_imag, Ft_sw, Ginv_sw, Wtf);
    sc_dft<<<64 * split, 256, 0, stream>>>(lhss, Ft_sw, XFp, nsteps);
    sc_mix<<<256, 256, 0, stream>>>(XFp, Wtf, M2, split);
    sc_idft<<<2048, 512, 0, stream>>>(M2, Ginv_sw, out);
}